// Round 5
// baseline (431.672 us; speedup 1.0000x reference)
//
#include <hip/hip_runtime.h>
#include <stdint.h>

#define B_N   16384
#define S_N   256
#define NCH   8
#define P_N   (B_N * S_N)      // 4194304 positions (b,s)
#define EPS_F 1e-5f

typedef float  f32x4  __attribute__((ext_vector_type(4)));
typedef float  f32x16 __attribute__((ext_vector_type(16)));
typedef __bf16 bf16x8 __attribute__((ext_vector_type(8)));
typedef unsigned int u32x4 __attribute__((ext_vector_type(4)));
typedef unsigned int u32x2 __attribute__((ext_vector_type(2)));

static __device__ __forceinline__ unsigned short f2bf(float f) {
  union { float f; unsigned u; } v; v.f = f;
  unsigned u = v.u;
  u += 0x7fffu + ((u >> 16) & 1u);          // RNE
  return (unsigned short)(u >> 16);
}
static __device__ __forceinline__ float bf2f(unsigned short h) {
  union { unsigned u; float f; } v; v.u = ((unsigned)h) << 16;
  return v.f;
}

typedef const __attribute__((address_space(1))) unsigned int* gas1_t;
typedef __attribute__((address_space(3))) unsigned int* las3_t;
// async global->LDS, 16B per lane; LDS dest must be linear (base + lane*16)
static __device__ __forceinline__ void gl16(const void* g, void* l) {
  __builtin_amdgcn_global_load_lds((gas1_t)(uintptr_t)g,
                                   (las3_t)(unsigned int)(uintptr_t)l, 16, 0, 0);
}

// ---------------- pass 1: per-channel stats partials + planar bf16 transpose ----------------
__global__ __launch_bounds__(256) void pass1_kernel(
    const float* __restrict__ x, unsigned short* __restrict__ xplan,
    float* __restrict__ partials)
{
  __shared__ float ps[4][32];
  const int t = threadIdx.x;
  const int q = t & 3;               // channel quad: interleaved channels 4q..4q+3
  const int pg = t >> 2;             // 0..63 position-group within tile
  float s[4] = {0.f,0.f,0.f,0.f}, ss[4] = {0.f,0.f,0.f,0.f};
  const f32x4* xv = (const f32x4*)x;

  for (int it = 0; it < 4; ++it) {
    size_t p0 = ((size_t)blockIdx.x * 4 + it) * 512 + (size_t)pg * 8;
    f32x4 v[8];
    #pragma unroll
    for (int j = 0; j < 8; ++j) v[j] = xv[(p0 + j) * 4 + q];
    #pragma unroll
    for (int j = 0; j < 8; ++j)
      #pragma unroll
      for (int k = 0; k < 4; ++k) { s[k] += v[j][k]; ss[k] += v[j][k] * v[j][k]; }
    #pragma unroll
    for (int j2 = 0; j2 < 4; ++j2) {
      u32x4 w;
      #pragma unroll
      for (int k = 0; k < 4; ++k)
        w[k] = (unsigned)f2bf(v[2*k][j2]) | ((unsigned)f2bf(v[2*k+1][j2]) << 16);
      *(u32x4*)(xplan + (size_t)(q * 4 + j2) * P_N + p0) = w;
    }
  }

  #pragma unroll
  for (int off = 32; off >= 4; off >>= 1) {
    #pragma unroll
    for (int k = 0; k < 4; ++k) { s[k] += __shfl_down(s[k], off); ss[k] += __shfl_down(ss[k], off); }
  }
  const int lane = t & 63, wid = t >> 6;
  if (lane < 4) {
    #pragma unroll
    for (int k = 0; k < 4; ++k) {
      ps[wid][lane * 4 + k]      = s[k];
      ps[wid][16 + lane * 4 + k] = ss[k];
    }
  }
  __syncthreads();
  if (t < 32)
    partials[blockIdx.x * 32 + t] = ps[0][t] + ps[1][t] + ps[2][t] + ps[3][t];
}

// ---------------- finalize: reduce partials -> A,C ----------------
__global__ __launch_bounds__(1024) void finalize_kernel(
    const float* __restrict__ partials, const float* __restrict__ g_in,
    const float* __restrict__ b_in, float* __restrict__ AC)
{
  __shared__ float acc[32][32];
  const int t = threadIdx.x;
  const int v = t & 31, chunk = t >> 5;
  float s = 0.f;
  for (int i = 0; i < 64; ++i)
    s += partials[(size_t)(chunk * 64 + i) * 32 + v];
  acc[chunk][v] = s;
  __syncthreads();
  if (t < 32) {
    float tot = 0.f;
    #pragma unroll
    for (int k = 0; k < 32; ++k) tot += acc[k][t];
    acc[0][t] = tot;
  }
  __syncthreads();
  if (t < 16) {
    float n = (float)P_N;
    float mu  = acc[0][t] / n;
    float var = acc[0][16 + t] / n - mu * mu;
    float A = g_in[t] * rsqrtf(var + EPS_F);
    AC[t] = A;
    AC[16 + t] = b_in[t] - mu * A;
  }
}

// ---------------- W prep: fp32 -> bf16 in fragment-native layout + rowsums ----------------
// W'[c][chunk16][khalf2][o256][j8]: a wave's B-frag load (o = lane&31, khalf = lane>>5)
// is two contiguous 512B segments -> perfectly coalesced global_load_dwordx4.
__global__ __launch_bounds__(256) void wprep_kernel(
    const float* __restrict__ Wr, const float* __restrict__ Wi,
    unsigned short* __restrict__ wrp, unsigned short* __restrict__ wip,
    float* __restrict__ RWr, float* __restrict__ RWi)
{
  __shared__ float sr[4], si[4];
  const int row = blockIdx.x, t = threadIdx.x;   // row = c*256 + o, t = k
  const int c = row >> 8, o = row & 255;
  const size_t idx = (size_t)row * 256 + t;
  float vr = Wr[idx], vi = Wi[idx];
  const size_t widx = ((size_t)((c * 16 + (t >> 4)) * 2 + ((t >> 3) & 1)) * 256 + o) * 8 + (t & 7);
  wrp[widx] = f2bf(vr);
  wip[widx] = f2bf(vi);
  float rr = vr, ri = vi;
  #pragma unroll
  for (int off = 32; off >= 1; off >>= 1) { rr += __shfl_down(rr, off); ri += __shfl_down(ri, off); }
  if ((t & 63) == 0) { sr[t >> 6] = rr; si[t >> 6] = ri; }
  __syncthreads();
  if (t == 0) {
    RWr[row] = sr[0] + sr[1] + sr[2] + sr[3];
    RWi[row] = si[0] + si[1] + si[2] + si[3];
  }
}

// ---------------- K terms ----------------
__global__ __launch_bounds__(256) void kterm_kernel(
    const float* __restrict__ AC, const float* __restrict__ RWr, const float* __restrict__ RWi,
    float* __restrict__ Kr, float* __restrict__ Ki)
{
  int idx = blockIdx.x * 256 + threadIdx.x;   // 2048 = c*256+o
  int c = idx >> 8;
  float Ci_ = AC[16 + 2*c], Cq_ = AC[16 + 2*c + 1];
  Kr[idx] = Ci_ * RWr[idx] - Cq_ * RWi[idx];
  Ki[idx] = Cq_ * RWr[idx] + Ci_ * RWi[idx];
}

static __device__ __forceinline__ void issue_x(
    const unsigned short* __restrict__ xplan, int c, int b0, char* xlds, int t)
{
  #pragma unroll
  for (int i = 0; i < 8; ++i) {
    const int plane = i >> 2, si = i & 3;
    const int L = plane * 16384 + si * 4096 + t * 16;
    const int row = si * 8 + (t >> 5);              // batch row 0..31
    const int gd = (t & 31) ^ (row & 7);            // data granule at this slot
    const char* g = (const char*)xplan
        + (((size_t)(2 * c + plane) * P_N + (size_t)(b0 + row) * 256) << 1) + (gd << 4);
    gl16(g, xlds + L);
  }
}

// ---------------- main: 32x32x16 MFMA, W streamed from L2 (no W LDS, 2 barriers/channel) --------
// 512 blocks x 256 thr (4 waves); M=32 rows/block; wave covers o-tile of 32 per oh-half.
__global__ __launch_bounds__(256, 3) void main_kernel(
    const unsigned short* __restrict__ xplan,
    const unsigned short* __restrict__ wrp,
    const unsigned short* __restrict__ wip,
    const float* __restrict__ AC,
    const float* __restrict__ Kr, const float* __restrict__ Ki,
    const float* __restrict__ Wfr, const float* __restrict__ Wfi,
    float* __restrict__ y)
{
  __shared__ char Xlds[32768];     // 2 planes x 32 rows x 512B, 16B-granule XOR swizzle (row&7)
  __shared__ float red[4][32][2];

  const int t = threadIdx.x;
  const int wid = t >> 6, lane = t & 63;
  const int ocol = lane & 31, khalf = lane >> 5;
  const int arow = ocol;                 // A-frag batch row = lane&31
  const int arow7 = arow & 7;
  const int b0 = blockIdx.x * 32;

  float pC0[16], pC1[16];
  #pragma unroll
  for (int i = 0; i < 16; ++i) { pC0[i] = 0.f; pC1[i] = 0.f; }

  const char* XiB = Xlds + arow * 512;
  const char* XqB = Xlds + 16384 + arow * 512;

  for (int c = 0; c < NCH; ++c) {
    __syncthreads();                       // all waves done reading Xlds (prev channel)
    issue_x(xplan, c, b0, Xlds, t);        // 8 async 16B/lane loads
    __syncthreads();                       // implicit vmcnt(0): X ready

    const float Ai_ = AC[2*c],      Aq_ = AC[2*c + 1];
    const float Cin = AC[16 + 2*c], Cqn = AC[16 + 2*c + 1];

    for (int oh = 0; oh < 2; ++oh) {
      const int o = oh * 128 + wid * 32 + ocol;
      // W' byte offset for (c, u=0, khalf, o): c*131072 + khalf*4096 + o*16; chunk stride 8192
      const char* brP = (const char*)wrp + (size_t)c * 131072 + khalf * 4096 + o * 16;
      const char* biP = (const char*)wip + (size_t)c * 131072 + khalf * 4096 + o * 16;

      f32x16 Srr, Sqr, Sii, Sqi;
      #pragma unroll
      for (int i = 0; i < 16; ++i) { Srr[i]=0.f; Sqr[i]=0.f; Sii[i]=0.f; Sqi[i]=0.f; }

      bf16x8 brA = *(const bf16x8*)(brP);
      bf16x8 biA = *(const bf16x8*)(biP);
      #pragma unroll 1
      for (int u = 0; u < 16; u += 2) {
        bf16x8 brB = *(const bf16x8*)(brP + (u + 1) * 8192);
        bf16x8 biB = *(const bf16x8*)(biP + (u + 1) * 8192);
        {
          const int axo = ((u * 2 + khalf) ^ arow7) << 4;
          bf16x8 axi = *(const bf16x8*)(XiB + axo);
          bf16x8 axq = *(const bf16x8*)(XqB + axo);
          Srr = __builtin_amdgcn_mfma_f32_32x32x16_bf16(axi, brA, Srr, 0,0,0);
          Sqr = __builtin_amdgcn_mfma_f32_32x32x16_bf16(axq, brA, Sqr, 0,0,0);
          Sii = __builtin_amdgcn_mfma_f32_32x32x16_bf16(axi, biA, Sii, 0,0,0);
          Sqi = __builtin_amdgcn_mfma_f32_32x32x16_bf16(axq, biA, Sqi, 0,0,0);
        }
        // prefetch chunk u+2 (u=14 reads 16 -> stays inside ws: spills into adjacent
        // ws buffers, values never used)
        brA = *(const bf16x8*)(brP + (u + 2) * 8192);
        biA = *(const bf16x8*)(biP + (u + 2) * 8192);
        {
          const int axo = (((u + 1) * 2 + khalf) ^ arow7) << 4;
          bf16x8 axi = *(const bf16x8*)(XiB + axo);
          bf16x8 axq = *(const bf16x8*)(XqB + axo);
          Srr = __builtin_amdgcn_mfma_f32_32x32x16_bf16(axi, brB, Srr, 0,0,0);
          Sqr = __builtin_amdgcn_mfma_f32_32x32x16_bf16(axq, brB, Sqr, 0,0,0);
          Sii = __builtin_amdgcn_mfma_f32_32x32x16_bf16(axi, biB, Sii, 0,0,0);
          Sqi = __builtin_amdgcn_mfma_f32_32x32x16_bf16(axq, biB, Sqi, 0,0,0);
        }
      }

      // epilogue: fold normalization affine + K terms, amp2 weighting, accumulate
      const int gidx = c * 256 + o;
      const float kr = Kr[gidx], ki = Ki[gidx];
      const float wfr = Wfr[gidx], wfi = Wfi[gidx];
      const int og = o >> 3, ob = (o & 7) * 2;
      #pragma unroll
      for (int q = 0; q < 16; ++q) {
        const int brow = (q & 3) + 8 * (q >> 2) + 4 * khalf;   // C/D row (m74/m101 layout)
        const int sb = brow * 512 + ((og ^ (brow & 7)) << 4) + ob;
        float xiv = Ai_ * bf2f(*(const unsigned short*)(Xlds + sb)) + Cin;
        float xqv = Aq_ * bf2f(*(const unsigned short*)(Xlds + 16384 + sb)) + Cqn;
        float cr = Ai_ * Srr[q] - Aq_ * Sqi[q] + kr;
        float ci = Aq_ * Sqr[q] + Ai_ * Sii[q] + ki;
        float amp2 = xiv * xiv + xqv * xqv;
        pC0[q] += amp2 * (cr * wfr - ci * wfi);
        pC1[q] += amp2 * (ci * wfr + cr * wfi);
      }
    }
  }

  // reduce over the 32 o-columns within each half-wave (halves hold different rows)
  #pragma unroll
  for (int off = 1; off < 32; off <<= 1) {
    #pragma unroll
    for (int q = 0; q < 16; ++q) {
      pC0[q] += __shfl_xor(pC0[q], off);
      pC1[q] += __shfl_xor(pC1[q], off);
    }
  }
  if ((lane & 31) == 0) {
    #pragma unroll
    for (int q = 0; q < 16; ++q) {
      const int brow = (q & 3) + 8 * (q >> 2) + 4 * khalf;
      red[wid][brow][0] = pC0[q];
      red[wid][brow][1] = pC1[q];
    }
  }
  __syncthreads();
  if (t < 64) {
    int bl = t >> 1, cc = t & 1;
    float v = red[0][bl][cc] + red[1][bl][cc] + red[2][bl][cc] + red[3][bl][cc];
    y[(size_t)(b0 + bl) * 2 + cc] = v;
  }
}

// ---------------- final batch LayerNorm over y (B,2) ----------------
__global__ __launch_bounds__(1024) void ln_kernel(
    const float* __restrict__ y, const float* __restrict__ g_out, const float* __restrict__ b_out,
    float* __restrict__ out)
{
  __shared__ float wsum[16][4];
  __shared__ float st[4];
  const int t = threadIdx.x;
  float s0 = 0.f, q0 = 0.f, s1 = 0.f, q1 = 0.f;
  for (int r = t; r < B_N; r += 1024) {
    float v0 = y[2*r], v1 = y[2*r + 1];
    s0 += v0; q0 += v0 * v0;
    s1 += v1; q1 += v1 * v1;
  }
  #pragma unroll
  for (int off = 32; off >= 1; off >>= 1) {
    s0 += __shfl_down(s0, off); q0 += __shfl_down(q0, off);
    s1 += __shfl_down(s1, off); q1 += __shfl_down(q1, off);
  }
  if ((t & 63) == 0) { int w = t >> 6; wsum[w][0]=s0; wsum[w][1]=q0; wsum[w][2]=s1; wsum[w][3]=q1; }
  __syncthreads();
  if (t == 0) {
    float S0=0.f,Q0=0.f,S1=0.f,Q1=0.f;
    for (int w = 0; w < 16; ++w) { S0+=wsum[w][0]; Q0+=wsum[w][1]; S1+=wsum[w][2]; Q1+=wsum[w][3]; }
    float n = (float)B_N;
    float mu0 = S0 / n, var0 = Q0 / n - mu0 * mu0;
    float mu1 = S1 / n, var1 = Q1 / n - mu1 * mu1;
    st[0] = mu0; st[1] = rsqrtf(var0 + EPS_F);
    st[2] = mu1; st[3] = rsqrtf(var1 + EPS_F);
  }
  __syncthreads();
  float g0 = g_out[0], g1 = g_out[1], bo0 = b_out[0], bo1 = b_out[1];
  float mu0 = st[0], rs0 = st[1], mu1 = st[2], rs1 = st[3];
  for (int r = t; r < B_N; r += 1024) {
    out[2*r]     = (y[2*r]     - mu0) * rs0 * g0 + bo0;
    out[2*r + 1] = (y[2*r + 1] - mu1) * rs1 * g1 + bo1;
  }
}

extern "C" void kernel_launch(void* const* d_in, const int* in_sizes, int n_in,
                              void* d_out, int out_size, void* d_ws, size_t ws_size,
                              hipStream_t stream) {
  (void)in_sizes; (void)n_in; (void)out_size; (void)ws_size;
  const float* x    = (const float*)d_in[0];
  // d_in[1] = h_0 (unused by the reference)
  const float* Wr   = (const float*)d_in[2];
  const float* Wi   = (const float*)d_in[3];
  const float* Wfr  = (const float*)d_in[4];
  const float* Wfi  = (const float*)d_in[5];
  const float* g_in = (const float*)d_in[6];
  const float* b_in = (const float*)d_in[7];
  const float* g_out= (const float*)d_in[8];
  const float* b_out= (const float*)d_in[9];
  float* out = (float*)d_out;

  char* ws = (char*)d_ws;
  float* AC    = (float*)(ws + 128);          // 32 f: A[16], C[16]
  float* RWr   = (float*)(ws + 256);          // 2048 f
  float* RWi   = (float*)(ws + 256 + 8192);
  float* Kr    = (float*)(ws + 256 + 16384);
  float* Ki    = (float*)(ws + 256 + 24576);
  float* y     = (float*)(ws + 33024);        // 32768 f (B x 2)
  // partials overlaps wrp: finalize consumes it BEFORE wprep writes wrp (same stream order)
  float* partials = (float*)(ws + 164096);    // 2048*32 f = 256 KB
  unsigned short* wrp = (unsigned short*)(ws + 164096);               // 1 MB, W' layout
  unsigned short* wip = (unsigned short*)(ws + 164096 + 1048576);     // 1 MB, W' layout
  unsigned short* xplan = (unsigned short*)(ws + 2261248);            // 128 MB: 16 planes of P_N bf16

  pass1_kernel<<<2048, 256, 0, stream>>>(x, xplan, partials);
  finalize_kernel<<<1, 1024, 0, stream>>>(partials, g_in, b_in, AC);
  wprep_kernel<<<2048, 256, 0, stream>>>(Wr, Wi, wrp, wip, RWr, RWi);
  kterm_kernel<<<8, 256, 0, stream>>>(AC, RWr, RWi, Kr, Ki);
  main_kernel<<<B_N / 32, 256, 0, stream>>>(xplan, wrp, wip, AC, Kr, Ki, Wfr, Wfi, y);
  ln_kernel<<<1, 1024, 0, stream>>>(y, g_out, b_out, out);
}

// Round 6
// 218.783 us; speedup vs baseline: 1.9731x; 1.9731x over previous
//
#include <hip/hip_runtime.h>
#include <stdint.h>

#define B_N   16384
#define S_N   256
#define NCH   8
#define P_N   (B_N * S_N)      // 4194304 positions (b,s)
#define EPS_F 1e-5f

typedef float  f32x4  __attribute__((ext_vector_type(4)));
typedef __bf16 bf16x8 __attribute__((ext_vector_type(8)));
typedef __bf16 bf16x4 __attribute__((ext_vector_type(4)));
typedef unsigned int u32x4 __attribute__((ext_vector_type(4)));
typedef unsigned int u32x2 __attribute__((ext_vector_type(2)));

static __device__ __forceinline__ unsigned short f2bf(float f) {
  union { float f; unsigned u; } v; v.f = f;
  unsigned u = v.u;
  u += 0x7fffu + ((u >> 16) & 1u);          // RNE
  return (unsigned short)(u >> 16);
}
static __device__ __forceinline__ float bf2f(unsigned short h) {
  union { unsigned u; float f; } v; v.u = ((unsigned)h) << 16;
  return v.f;
}

typedef const __attribute__((address_space(1))) unsigned int* gas1_t;
typedef __attribute__((address_space(3))) unsigned int* las3_t;
// async global->LDS, 16B per lane; LDS dest must be linear (base + lane*16)
static __device__ __forceinline__ void gl16(const void* g, void* l) {
  __builtin_amdgcn_global_load_lds((gas1_t)(uintptr_t)g,
                                   (las3_t)(unsigned int)(uintptr_t)l, 16, 0, 0);
}

// ---------------- pass 1: per-channel stats partials + planar bf16 transpose ----------------
__global__ __launch_bounds__(256) void pass1_kernel(
    const float* __restrict__ x, unsigned short* __restrict__ xplan,
    float* __restrict__ partials)
{
  __shared__ float ps[4][32];
  const int t = threadIdx.x;
  const int q = t & 3;               // channel quad: interleaved channels 4q..4q+3
  const int pg = t >> 2;             // 0..63 position-group within tile
  float s[4] = {0.f,0.f,0.f,0.f}, ss[4] = {0.f,0.f,0.f,0.f};
  const f32x4* xv = (const f32x4*)x;

  for (int it = 0; it < 4; ++it) {
    size_t p0 = ((size_t)blockIdx.x * 4 + it) * 512 + (size_t)pg * 8;
    f32x4 v[8];
    #pragma unroll
    for (int j = 0; j < 8; ++j) v[j] = xv[(p0 + j) * 4 + q];
    #pragma unroll
    for (int j = 0; j < 8; ++j)
      #pragma unroll
      for (int k = 0; k < 4; ++k) { s[k] += v[j][k]; ss[k] += v[j][k] * v[j][k]; }
    #pragma unroll
    for (int j2 = 0; j2 < 4; ++j2) {
      u32x4 w;
      #pragma unroll
      for (int k = 0; k < 4; ++k)
        w[k] = (unsigned)f2bf(v[2*k][j2]) | ((unsigned)f2bf(v[2*k+1][j2]) << 16);
      *(u32x4*)(xplan + (size_t)(q * 4 + j2) * P_N + p0) = w;
    }
  }

  #pragma unroll
  for (int off = 32; off >= 4; off >>= 1) {
    #pragma unroll
    for (int k = 0; k < 4; ++k) { s[k] += __shfl_down(s[k], off); ss[k] += __shfl_down(ss[k], off); }
  }
  const int lane = t & 63, wid = t >> 6;
  if (lane < 4) {
    #pragma unroll
    for (int k = 0; k < 4; ++k) {
      ps[wid][lane * 4 + k]      = s[k];
      ps[wid][16 + lane * 4 + k] = ss[k];
    }
  }
  __syncthreads();
  if (t < 32)
    partials[blockIdx.x * 32 + t] = ps[0][t] + ps[1][t] + ps[2][t] + ps[3][t];
}

// ---------------- finalize: reduce partials -> A,C ----------------
__global__ __launch_bounds__(1024) void finalize_kernel(
    const float* __restrict__ partials, const float* __restrict__ g_in,
    const float* __restrict__ b_in, float* __restrict__ AC)
{
  __shared__ float acc[32][32];
  const int t = threadIdx.x;
  const int v = t & 31, chunk = t >> 5;
  float s = 0.f;
  for (int i = 0; i < 64; ++i)
    s += partials[(size_t)(chunk * 64 + i) * 32 + v];
  acc[chunk][v] = s;
  __syncthreads();
  if (t < 32) {
    float tot = 0.f;
    #pragma unroll
    for (int k = 0; k < 32; ++k) tot += acc[k][t];
    acc[0][t] = tot;
  }
  __syncthreads();
  if (t < 16) {
    float n = (float)P_N;
    float mu  = acc[0][t] / n;
    float var = acc[0][16 + t] / n - mu * mu;
    float A = g_in[t] * rsqrtf(var + EPS_F);
    AC[t] = A;
    AC[16 + t] = b_in[t] - mu * A;
  }
}

// ---------------- W prep: fp32 -> bf16 in chunked granule layout + rowsums ----------------
// W'[c][u8][o256][tt2][g4][j8]: one 128B row per (c,u,o); staged to LDS via pre-swizzled src.
__global__ __launch_bounds__(256) void wprep_kernel(
    const float* __restrict__ Wr, const float* __restrict__ Wi,
    unsigned short* __restrict__ wp,
    float* __restrict__ RWr, float* __restrict__ RWi)
{
  __shared__ float sr[4], si[4];
  const int row = blockIdx.x, t = threadIdx.x;   // row = c*256 + o, t = k
  const int c = row >> 8, o = row & 255;
  const size_t idx = (size_t)row * 256 + t;
  float vr = Wr[idx], vi = Wi[idx];
  const int u = t >> 5, g = (t >> 3) & 3, j = t & 7;
  const size_t base = ((size_t)((c * 8 + u) * 256 + o) << 6) + g * 8 + j;
  wp[base]      = f2bf(vr);    // tt=0 (Wr)
  wp[base + 32] = f2bf(vi);    // tt=1 (Wi)
  float rr = vr, ri = vi;
  #pragma unroll
  for (int off = 32; off >= 1; off >>= 1) { rr += __shfl_down(rr, off); ri += __shfl_down(ri, off); }
  if ((t & 63) == 0) { sr[t >> 6] = rr; si[t >> 6] = ri; }
  __syncthreads();
  if (t == 0) {
    RWr[row] = sr[0] + sr[1] + sr[2] + sr[3];
    RWi[row] = si[0] + si[1] + si[2] + si[3];
  }
}

// ---------------- K terms ----------------
__global__ __launch_bounds__(256) void kterm_kernel(
    const float* __restrict__ AC, const float* __restrict__ RWr, const float* __restrict__ RWi,
    float* __restrict__ Kr, float* __restrict__ Ki)
{
  int idx = blockIdx.x * 256 + threadIdx.x;   // 2048 = c*256+o
  int c = idx >> 8;
  float Ci_ = AC[16 + 2*c], Cq_ = AC[16 + 2*c + 1];
  Kr[idx] = Ci_ * RWr[idx] - Cq_ * RWi[idx];
  Ki[idx] = Cq_ * RWr[idx] + Ci_ * RWi[idx];
}

// one pipeline phase's staging: X chunk (8KB, 1 gl16/thr) + W chunk (32KB, 4 gl16/thr) = 5 loads
static __device__ __forceinline__ void issue_phase(
    const unsigned short* __restrict__ xplan, const unsigned short* __restrict__ wp,
    int p, int b0, int t, char* xbuf, char* wbuf)
{
  const int c = p >> 3, u = p & 7;
  {
    const int row = t >> 3, slot = t & 7;
    const int sd = slot ^ (row & 7);            // data granule (pl,g) at this LDS slot
    const int pl = sd >> 2, g = sd & 3;
    const char* gsrc = (const char*)xplan +
        (((size_t)(2 * c + pl) * P_N + (size_t)(b0 + row) * 256 + u * 32 + g * 8) << 1);
    gl16(gsrc, xbuf + t * 16);
  }
  #pragma unroll
  for (int i = 0; i < 4; ++i) {
    const int o = i * 64 + (t >> 3), slot = t & 7;
    const int gd = slot ^ (o & 7);
    const char* gsrc = (const char*)wp +
        (((size_t)((c * 8 + u) * 256 + o)) << 7) + (gd << 4);
    gl16(gsrc, wbuf + i * 8192 + t * 16);
  }
}

// ---------------- main: chunk-pipelined complex MFMA + amp2-weighted contraction ----------------
// 256 blocks x 512 thr (8 waves = 2m x 4o); M=64 rows/block; X+W both flow as k=32 chunks
// through 3-buffered LDS; one counted vmcnt(5) + raw barrier per phase (64 phases).
__global__ __launch_bounds__(512, 2) void main_kernel(
    const unsigned short* __restrict__ xplan,
    const unsigned short* __restrict__ wp,
    const float* __restrict__ AC,
    const float* __restrict__ Kr, const float* __restrict__ Ki,
    const float* __restrict__ Wfr, const float* __restrict__ Wfi,
    float* __restrict__ y)
{
  __shared__ char Xc[3][8192];            // [row64][pl2|g4 granules XOR row&7][16B]
  __shared__ char Wc[3][32768];           // [o256][tt2|g4 granules XOR o&7][16B]
  __shared__ unsigned short amp2s[64][256];
  __shared__ float red[4][64][2];
  __shared__ float acs[32];

  const int t = threadIdx.x;
  const int wid = t >> 6, lane = t & 63;
  const int mw = wid >> 2, ow = wid & 3;     // wave grid: 2 m-groups x 4 o-groups
  const int col = lane & 15, kg = lane >> 4;
  const int c7 = col & 7;
  const int b0 = blockIdx.x * 64;
  // amp2-slice lane constants
  const int srow = t >> 3, aoq = t & 7;
  const int ag = aoq >> 1, ah = aoq & 1;

  if (t < 32) acs[t] = AC[t];

  float pCr[2][4], pCi[2][4];
  #pragma unroll
  for (int m = 0; m < 2; ++m)
    #pragma unroll
    for (int r = 0; r < 4; ++r) { pCr[m][r] = 0.f; pCi[m][r] = 0.f; }

  f32x4 acc[2][4][4];   // [mf][nf][Srr,Sqr,Sii,Sqi]

  issue_phase(xplan, wp, 0, b0, t, Xc[0], Wc[0]);
  issue_phase(xplan, wp, 1, b0, t, Xc[1], Wc[1]);

  float Ai_ = 0.f, Aq_ = 0.f, Cin = 0.f, Cqn = 0.f;

  #pragma unroll 1
  for (int p = 0; p < 64; ++p) {
    const int c = p >> 3, u = p & 7;
    if (p == 63) { asm volatile("s_waitcnt vmcnt(0)" ::: "memory"); }
    else         { asm volatile("s_waitcnt vmcnt(5)" ::: "memory"); }
    __builtin_amdgcn_s_barrier();          // raw: prefetch (p+1) stays in flight
    if (p + 2 < 64)
      issue_phase(xplan, wp, p + 2, b0, t, Xc[(p + 2) % 3], Wc[(p + 2) % 3]);
    __builtin_amdgcn_sched_barrier(0);

    if (u == 0) {
      Ai_ = acs[2*c]; Aq_ = acs[2*c + 1]; Cin = acs[16 + 2*c]; Cqn = acs[16 + 2*c + 1];
      #pragma unroll
      for (int mf = 0; mf < 2; ++mf)
        #pragma unroll
        for (int nf = 0; nf < 4; ++nf)
          #pragma unroll
          for (int s = 0; s < 4; ++s)
            acc[mf][nf][s] = (f32x4){0.f,0.f,0.f,0.f};
    }

    const char* Xb = Xc[p % 3];
    const char* Wb = Wc[p % 3];

    bf16x8 a[2][2];   // [mf][plane]
    #pragma unroll
    for (int mf = 0; mf < 2; ++mf)
      #pragma unroll
      for (int pl = 0; pl < 2; ++pl) {
        const int row = mw * 32 + mf * 16 + col;
        a[mf][pl] = *(const bf16x8*)(Xb + row * 128 + (((pl * 4 + kg) ^ c7) << 4));
      }
    bf16x8 b[4][2];   // [nf][type]
    #pragma unroll
    for (int nf = 0; nf < 4; ++nf)
      #pragma unroll
      for (int tt = 0; tt < 2; ++tt) {
        const int o = ow * 64 + nf * 16 + col;
        b[nf][tt] = *(const bf16x8*)(Wb + o * 128 + (((tt * 4 + kg) ^ c7) << 4));
      }
    #pragma unroll
    for (int mf = 0; mf < 2; ++mf)
      #pragma unroll
      for (int nf = 0; nf < 4; ++nf) {
        acc[mf][nf][0] = __builtin_amdgcn_mfma_f32_16x16x32_bf16(a[mf][0], b[nf][0], acc[mf][nf][0], 0,0,0);
        acc[mf][nf][1] = __builtin_amdgcn_mfma_f32_16x16x32_bf16(a[mf][1], b[nf][0], acc[mf][nf][1], 0,0,0);
        acc[mf][nf][2] = __builtin_amdgcn_mfma_f32_16x16x32_bf16(a[mf][0], b[nf][1], acc[mf][nf][2], 0,0,0);
        acc[mf][nf][3] = __builtin_amdgcn_mfma_f32_16x16x32_bf16(a[mf][1], b[nf][1], acc[mf][nf][3], 0,0,0);
      }

    {   // amp2 slice for this chunk's 32 o-positions (s==o), into persistent amp2s
      bf16x4 xi = *(const bf16x4*)(Xb + srow * 128 + (((0 + ag) ^ (srow & 7)) << 4) + ah * 8);
      bf16x4 xq = *(const bf16x4*)(Xb + srow * 128 + (((4 + ag) ^ (srow & 7)) << 4) + ah * 8);
      unsigned short w[4];
      #pragma unroll
      for (int e = 0; e < 4; ++e) {
        float xiv = Ai_ * (float)xi[e] + Cin;
        float xqv = Aq_ * (float)xq[e] + Cqn;
        w[e] = f2bf(xiv * xiv + xqv * xqv);
      }
      const int og = u * 32 + aoq * 4;
      u32x2 pw;
      pw[0] = (unsigned)w[0] | ((unsigned)w[1] << 16);
      pw[1] = (unsigned)w[2] | ((unsigned)w[3] << 16);
      *(u32x2*)((char*)&amp2s[0][0] + srow * 512 + og * 2) = pw;
    }

    if (u == 7) {
      __builtin_amdgcn_s_barrier();        // all amp2 slices of channel c written
      #pragma unroll
      for (int nf = 0; nf < 4; ++nf) {
        const int o = ow * 64 + nf * 16 + col;
        const int gidx = c * 256 + o;
        const float kr = Kr[gidx], ki = Ki[gidx];
        const float wfr = Wfr[gidx], wfi = Wfi[gidx];
        #pragma unroll
        for (int mf = 0; mf < 2; ++mf) {
          const int rb = mw * 32 + mf * 16 + kg * 4;
          #pragma unroll
          for (int r = 0; r < 4; ++r) {
            float amp = bf2f(amp2s[rb + r][o]);
            float cr = Ai_ * acc[mf][nf][0][r] - Aq_ * acc[mf][nf][3][r] + kr;
            float ci = Aq_ * acc[mf][nf][1][r] + Ai_ * acc[mf][nf][2][r] + ki;
            pCr[mf][r] += amp * (cr * wfr - ci * wfi);
            pCi[mf][r] += amp * (ci * wfr + cr * wfi);
          }
        }
      }
    }
  }

  // reduce over 16 o-columns within each lane group
  #pragma unroll
  for (int off = 1; off < 16; off <<= 1) {
    #pragma unroll
    for (int m = 0; m < 2; ++m)
      #pragma unroll
      for (int r = 0; r < 4; ++r) {
        pCr[m][r] += __shfl_xor(pCr[m][r], off);
        pCi[m][r] += __shfl_xor(pCi[m][r], off);
      }
  }
  if (col == 0) {
    #pragma unroll
    for (int m = 0; m < 2; ++m)
      #pragma unroll
      for (int r = 0; r < 4; ++r) {
        const int row = mw * 32 + m * 16 + kg * 4 + r;
        red[ow][row][0] = pCr[m][r];
        red[ow][row][1] = pCi[m][r];
      }
  }
  __syncthreads();
  if (t < 128) {
    const int row = t >> 1, cc = t & 1;
    y[(size_t)(b0 + row) * 2 + cc] =
        red[0][row][cc] + red[1][row][cc] + red[2][row][cc] + red[3][row][cc];
  }
}

// ---------------- final batch LayerNorm over y (B,2) ----------------
__global__ __launch_bounds__(1024) void ln_kernel(
    const float* __restrict__ y, const float* __restrict__ g_out, const float* __restrict__ b_out,
    float* __restrict__ out)
{
  __shared__ float wsum[16][4];
  __shared__ float st[4];
  const int t = threadIdx.x;
  float s0 = 0.f, q0 = 0.f, s1 = 0.f, q1 = 0.f;
  for (int r = t; r < B_N; r += 1024) {
    float v0 = y[2*r], v1 = y[2*r + 1];
    s0 += v0; q0 += v0 * v0;
    s1 += v1; q1 += v1 * v1;
  }
  #pragma unroll
  for (int off = 32; off >= 1; off >>= 1) {
    s0 += __shfl_down(s0, off); q0 += __shfl_down(q0, off);
    s1 += __shfl_down(s1, off); q1 += __shfl_down(q1, off);
  }
  if ((t & 63) == 0) { int w = t >> 6; wsum[w][0]=s0; wsum[w][1]=q0; wsum[w][2]=s1; wsum[w][3]=q1; }
  __syncthreads();
  if (t == 0) {
    float S0=0.f,Q0=0.f,S1=0.f,Q1=0.f;
    for (int w = 0; w < 16; ++w) { S0+=wsum[w][0]; Q0+=wsum[w][1]; S1+=wsum[w][2]; Q1+=wsum[w][3]; }
    float n = (float)B_N;
    float mu0 = S0 / n, var0 = Q0 / n - mu0 * mu0;
    float mu1 = S1 / n, var1 = Q1 / n - mu1 * mu1;
    st[0] = mu0; st[1] = rsqrtf(var0 + EPS_F);
    st[2] = mu1; st[3] = rsqrtf(var1 + EPS_F);
  }
  __syncthreads();
  float g0 = g_out[0], g1 = g_out[1], bo0 = b_out[0], bo1 = b_out[1];
  float mu0 = st[0], rs0 = st[1], mu1 = st[2], rs1 = st[3];
  for (int r = t; r < B_N; r += 1024) {
    out[2*r]     = (y[2*r]     - mu0) * rs0 * g0 + bo0;
    out[2*r + 1] = (y[2*r + 1] - mu1) * rs1 * g1 + bo1;
  }
}

extern "C" void kernel_launch(void* const* d_in, const int* in_sizes, int n_in,
                              void* d_out, int out_size, void* d_ws, size_t ws_size,
                              hipStream_t stream) {
  (void)in_sizes; (void)n_in; (void)out_size; (void)ws_size;
  const float* x    = (const float*)d_in[0];
  // d_in[1] = h_0 (unused by the reference)
  const float* Wr   = (const float*)d_in[2];
  const float* Wi   = (const float*)d_in[3];
  const float* Wfr  = (const float*)d_in[4];
  const float* Wfi  = (const float*)d_in[5];
  const float* g_in = (const float*)d_in[6];
  const float* b_in = (const float*)d_in[7];
  const float* g_out= (const float*)d_in[8];
  const float* b_out= (const float*)d_in[9];
  float* out = (float*)d_out;

  char* ws = (char*)d_ws;
  float* AC    = (float*)(ws + 128);          // 32 f: A[16], C[16]
  float* RWr   = (float*)(ws + 256);          // 2048 f
  float* RWi   = (float*)(ws + 256 + 8192);
  float* Kr    = (float*)(ws + 256 + 16384);
  float* Ki    = (float*)(ws + 256 + 24576);
  float* y     = (float*)(ws + 33024);        // 32768 f (B x 2)
  // partials overlaps wp: finalize consumes it BEFORE wprep writes wp (same stream order)
  float* partials = (float*)(ws + 164096);    // 2048*32 f = 256 KB
  unsigned short* wp = (unsigned short*)(ws + 164096);                // 2 MB, W' chunk layout
  unsigned short* xplan = (unsigned short*)(ws + 2261248);            // 128 MB: 16 planes of P_N bf16

  pass1_kernel<<<2048, 256, 0, stream>>>(x, xplan, partials);
  finalize_kernel<<<1, 1024, 0, stream>>>(partials, g_in, b_in, AC);
  wprep_kernel<<<2048, 256, 0, stream>>>(Wr, Wi, wp, RWr, RWi);
  kterm_kernel<<<8, 256, 0, stream>>>(AC, RWr, RWi, Kr, Ki);
  main_kernel<<<B_N / 64, 512, 0, stream>>>(xplan, wp, AC, Kr, Ki, Wfr, Wfi, y);
  ln_kernel<<<1, 1024, 0, stream>>>(y, g_out, b_out, out);
}